// Round 1
// 53.879 us; speedup vs baseline: 1.1242x; 1.1242x over previous
//
#include <hip/hip_runtime.h>
#include <hip/hip_bf16.h>

#define BB 64
#define NN 32
#define IND 128
#define HD 512
#define OD 256
#define NPERM 992

typedef __attribute__((ext_vector_type(8))) _Float16 half8;
typedef __attribute__((ext_vector_type(4))) _Float16 half4;
typedef __attribute__((ext_vector_type(4))) float f32x4;
typedef __attribute__((ext_vector_type(16))) float f32x16;

__device__ __forceinline__ half8 relu8(half8 x) {
    half8 z = 0;
    return __builtin_elementwise_max(x, z);
}

// ------- prep A:
//   blocks   0..63 : W2 [512,512] f32 -> W2t [c][k] f16 (transposed) + out init = NPERM*b3
//   blocks  64..95 : W1 [256,512] f32 -> W1t [h][k] f16 (transposed)
//   blocks  96..111: x  f32 -> x16 f16 (linear copy/convert)
__global__ void kprepA(const float* __restrict__ W2, _Float16* __restrict__ W2t,
                       const float* __restrict__ b3, float* __restrict__ out,
                       const float* __restrict__ W1, _Float16* __restrict__ W1t,
                       const float* __restrict__ x, _Float16* __restrict__ x16) {
    __shared__ float smem[64 * 65];  // 16.25KB transpose tile
    const int bid = blockIdx.x;
    const int t = threadIdx.x;

    if (bid < 64) {
        // ---- init out[bid] = NPERM * b3 ----
        out[(size_t)bid * OD + t] = (float)NPERM * b3[t];
        // ---- W2 [512,512] f32 -> W2t [c][k] f16 (transposed) ----
        float (*tile)[65] = (float (*)[65])smem;
        int k0 = (bid & 7) * 64, c0 = (bid >> 3) * 64;
        int cin = t & 63, r0 = t >> 6;
#pragma unroll
        for (int rr = 0; rr < 16; ++rr) {
            int r = r0 * 16 + rr;
            tile[r][cin] = W2[(k0 + r) * HD + c0 + cin];
        }
        __syncthreads();
        int kout = t & 63, c0r = t >> 6;
#pragma unroll
        for (int rr = 0; rr < 16; ++rr) {
            int c = c0r * 16 + rr;
            W2t[(size_t)(c0 + c) * HD + k0 + kout] = (_Float16)tile[kout][c];
        }
    } else if (bid < 96) {
        // ---- W1 [256,512] f32 -> W1t [h=512][k=256] f16 ----
        int bid2 = bid - 64;
        float (*tile)[65] = (float (*)[65])smem;
        int k0 = (bid2 & 3) * 64, h0 = (bid2 >> 2) * 64;
        int cin = t & 63, r0 = t >> 6;
#pragma unroll
        for (int rr = 0; rr < 16; ++rr) {
            int r = r0 * 16 + rr;
            tile[r][cin] = W1[(k0 + r) * HD + h0 + cin];
        }
        __syncthreads();
        int kout = t & 63, c0r = t >> 6;
#pragma unroll
        for (int rr = 0; rr < 16; ++rr) {
            int c = c0r * 16 + rr;
            W1t[(size_t)(h0 + c) * 256 + k0 + kout] = (_Float16)tile[kout][c];
        }
    } else {
        // ---- x -> x16 (f16, linear [b][n][k]) ----
        int bid3 = bid - 96;
#pragma unroll
        for (int it = 0; it < 8; ++it) {
            int c = t + it * 256;                          // 0..2047 chunks of 8
            size_t base = ((size_t)bid3 * 2048 + c) * 8;   // element index
            const float* src = x + base;
            float4 f0 = *(const float4*)src;
            float4 f1 = *(const float4*)(src + 4);
            half8 h;
            h[0] = (_Float16)f0.x; h[1] = (_Float16)f0.y;
            h[2] = (_Float16)f0.z; h[3] = (_Float16)f0.w;
            h[4] = (_Float16)f1.x; h[5] = (_Float16)f1.y;
            h[6] = (_Float16)f1.z; h[7] = (_Float16)f1.w;
            *(half8*)(x16 + base) = h;
        }
    }
}

// ------- prep B: U' = x@W1a + b1, V = x@W1b via MFMA f16, no LDS.
// grid (4, 64): g = blockIdx.x selects {U-lo, U-hi, V-lo, V-hi} 256-col group; b = blockIdx.y.
// 512 threads = 8 waves; wave w owns 32 h-cols. A = x16[b] rows (32 n), B = W1t rows (h),
// K = 128 (8 steps of 16). Both frags are direct 16B global loads (L1/L2-hot).
__global__ __launch_bounds__(512) void k1m(const _Float16* __restrict__ x16,
                                           const _Float16* __restrict__ W1t,
                                           const float* __restrict__ b1,
                                           _Float16* __restrict__ U, _Float16* __restrict__ Vo) {
    const int g = blockIdx.x;
    const int b = blockIdx.y;
    const int t = threadIdx.x;
    const int lane = t & 63, wv = t >> 6;
    const int l31 = lane & 31, hi = lane >> 5;
    const int h0 = (g & 1) * 256;     // output h-col base
    const int koff = (g >> 1) * 128;  // 0 = W1a (U), 128 = W1b (V)
    const int hglob = h0 + wv * 32 + l31;

    const char* abase = (const char*)x16 + (size_t)(b * NN + l31) * (IND * 2);
    const char* bbase = (const char*)W1t + (size_t)hglob * (256 * 2) + koff * 2;

    f32x16 acc;
#pragma unroll
    for (int r = 0; r < 16; ++r) acc[r] = 0.f;

#pragma unroll
    for (int ks = 0; ks < 8; ++ks) {
        int kb = ks * 32 + hi * 16;  // byte offset: k = ks*16 + hi*8
        half8 a  = *(const half8*)(abase + kb);
        half8 bf = *(const half8*)(bbase + kb);
        acc = __builtin_amdgcn_mfma_f32_32x32x16_f16(a, bf, acc, 0, 0, 0);
    }

    // C layout: col = lane&31 (h), row = (r&3) + 8*(r>>2) + 4*hi (n)
    float bias = (g < 2) ? b1[hglob] : 0.f;
    _Float16* dst = ((g < 2) ? U : Vo) + (size_t)(b * NN) * HD + hglob;
#pragma unroll
    for (int r = 0; r < 16; ++r) {
        int row = (r & 3) + 8 * (r >> 2) + 4 * hi;
        dst[(size_t)row * HD] = (_Float16)(acc[r] + bias);
    }
}

// ---------------- main: B + V + U resident in LDS; K-loop = LDS only; fused W3 epilogue ----------------
// grid (8, 64): blockIdx.x = 64-col chunk, blockIdx.y = b. 512 threads = 8 waves (2/SIMD).
// LDS 128KB (B 64K swz + V 32K swz + U 32K linear) + red/hred 2.25KB.
// Wave w owns rows [w*128, +128) x all 64 cols: acc[4][2] = 128 AGPR.
// Epilogue: masked col-sums -> LDS reduce -> 64x256 GEMV vs W3 -> atomicAdd into out.
#define VOFF 65536
#define UOFF 98304
__global__ __launch_bounds__(512, 2) void k2(
    const _Float16* __restrict__ U, const _Float16* __restrict__ V,
    const _Float16* __restrict__ W2t, const float* __restrict__ b2,
    const float* __restrict__ W3, float* __restrict__ out) {
    __shared__ _Float16 sm[(64 + 32 + 32) * HD];  // 131072 bytes
    __shared__ float red[8][64];
    __shared__ float hred[64];
    char* smb = (char*)sm;

    const int b = blockIdx.y;
    const int cb0 = blockIdx.x * 64;
    const int t = threadIdx.x;
    const int lane = t & 63, wid = t >> 6;

    // ---- merged staging: B (ii 0..7), V (ii 8..11), U (ii 12..15) ----
    {
        const _Float16* bsrc = W2t + (size_t)cb0 * HD;
        const _Float16* vsrc = V + (size_t)b * NN * HD;
        const _Float16* usrc = U + (size_t)b * NN * HD;
#pragma unroll
        for (int ii = 0; ii < 16; ++ii) {
            int id = t + (ii < 8 ? ii : (ii & 3)) * 512;  // B: 0..4095; V/U: 0..2047
            int r = id >> 6, m = id & 63;
            if (ii < 8) {
                uint4 w = *(const uint4*)(bsrc + (size_t)r * HD + m * 8);
                unsigned off = (unsigned)(r * 1024 + ((m * 16) ^ ((r & 15) << 4)));
                *(uint4*)(smb + off) = w;
            } else if (ii < 12) {
                uint4 w = *(const uint4*)(vsrc + (size_t)r * HD + m * 8);
                unsigned off = (unsigned)(VOFF + r * 1024 + ((m * 16) ^ ((r & 15) << 4)));
                *(uint4*)(smb + off) = w;
            } else {
                uint4 w = *(const uint4*)(usrc + (size_t)r * HD + m * 8);
                *(uint4*)(smb + UOFF + r * 1024 + m * 16) = w;
            }
        }
    }
    __syncthreads();

    const int l31 = lane & 31;
    const int hi = (lane >> 5);          // 0/1
    const unsigned sw = (unsigned)((l31 & 15) << 4);   // shared swizzle for V,B0,B1
    const unsigned ubase = (unsigned)(UOFF + wid * 4 * 1024 + hi * 16);
    const unsigned vbase = (unsigned)(VOFF + l31 * 1024);
    const unsigned b0base = (unsigned)(l31 * 1024);
    const unsigned b1base = (unsigned)((32 + l31) * 1024);

    f32x16 acc[4][2];
#pragma unroll
    for (int rf = 0; rf < 4; ++rf)
#pragma unroll
        for (int cf = 0; cf < 2; ++cf)
#pragma unroll
            for (int r = 0; r < 16; ++r) acc[rf][cf][r] = 0.f;

    // ---- prefetch ks=0 ----
    half8 pU0, pU1, pU2, pU3, pV, pB0, pB1;
    {
        unsigned kx = ((unsigned)(hi * 16)) ^ sw;
        pU0 = *(const half8*)(smb + ubase + 0 * 1024);
        pU1 = *(const half8*)(smb + ubase + 1 * 1024);
        pU2 = *(const half8*)(smb + ubase + 2 * 1024);
        pU3 = *(const half8*)(smb + ubase + 3 * 1024);
        pV  = *(const half8*)(smb + vbase + kx);
        pB0 = *(const half8*)(smb + b0base + kx);
        pB1 = *(const half8*)(smb + b1base + kx);
    }

#pragma unroll
    for (int ks = 0; ks < 32; ++ks) {
        half8 cU0 = pU0, cU1 = pU1, cU2 = pU2, cU3 = pU3;
        half8 cV = pV, cB0 = pB0, cB1 = pB1;
        if (ks < 31) {
            int kn = ks + 1;
            unsigned kx = ((unsigned)(kn * 32 + hi * 16)) ^ sw;
            pU0 = *(const half8*)(smb + ubase + 0 * 1024 + kn * 32);
            pU1 = *(const half8*)(smb + ubase + 1 * 1024 + kn * 32);
            pU2 = *(const half8*)(smb + ubase + 2 * 1024 + kn * 32);
            pU3 = *(const half8*)(smb + ubase + 3 * 1024 + kn * 32);
            pV  = *(const half8*)(smb + vbase + kx);
            pB0 = *(const half8*)(smb + b0base + kx);
            pB1 = *(const half8*)(smb + b1base + kx);
        }

        // A build: relu(U + V) in packed f16 (v_pk_add_f16 + v_pk_max_f16)
        half8 af0 = relu8(cU0 + cV);
        half8 af1 = relu8(cU1 + cV);
        half8 af2 = relu8(cU2 + cV);
        half8 af3 = relu8(cU3 + cV);

        __builtin_amdgcn_s_setprio(1);
        acc[0][0] = __builtin_amdgcn_mfma_f32_32x32x16_f16(af0, cB0, acc[0][0], 0, 0, 0);
        acc[0][1] = __builtin_amdgcn_mfma_f32_32x32x16_f16(af0, cB1, acc[0][1], 0, 0, 0);
        acc[1][0] = __builtin_amdgcn_mfma_f32_32x32x16_f16(af1, cB0, acc[1][0], 0, 0, 0);
        acc[1][1] = __builtin_amdgcn_mfma_f32_32x32x16_f16(af1, cB1, acc[1][1], 0, 0, 0);
        acc[2][0] = __builtin_amdgcn_mfma_f32_32x32x16_f16(af2, cB0, acc[2][0], 0, 0, 0);
        acc[2][1] = __builtin_amdgcn_mfma_f32_32x32x16_f16(af2, cB1, acc[2][1], 0, 0, 0);
        acc[3][0] = __builtin_amdgcn_mfma_f32_32x32x16_f16(af3, cB0, acc[3][0], 0, 0, 0);
        acc[3][1] = __builtin_amdgcn_mfma_f32_32x32x16_f16(af3, cB1, acc[3][1], 0, 0, 0);
        __builtin_amdgcn_s_setprio(0);
    }

    // ---- epilogue 1: h2 = relu(C + b2), mask diagonal, per-wave col-sums -> red ----
    float scf[2];
#pragma unroll
    for (int cf = 0; cf < 2; ++cf) {
        int col = cb0 + cf * 32 + l31;
        float b2v = b2[col];
        float s = 0.f;
#pragma unroll
        for (int rf = 0; rf < 4; ++rf) {
            int i_idx = wid * 4 + rf;
#pragma unroll
            for (int r = 0; r < 16; ++r) {
                int row = (r & 3) + 8 * (r >> 2) + 4 * hi;  // j index
                float h2 = fmaxf(acc[rf][cf][r] + b2v, 0.f);
                if (row != i_idx) s += h2;  // mask i==j
            }
        }
        s += __shfl_xor(s, 32);
        scf[cf] = s;
    }
    if (lane < 32) {
        red[wid][l31] = scf[0];
        red[wid][32 + l31] = scf[1];
    }
    __syncthreads();

    // ---- epilogue 2: reduce across waves -> hred[64] ----
    if (t < 64) {
        float h = 0.f;
#pragma unroll
        for (int w = 0; w < 8; ++w) h += red[w][t];
        hred[t] = h;
    }
    __syncthreads();

    // ---- epilogue 3: GEMV vs W3 panel [cb0..cb0+64) x 256, atomic into out ----
    {
        int o = t & 255, g = t >> 8;  // g = 0/1, 32 k's each
        const float* w3p = W3 + ((size_t)(cb0 + g * 32)) * OD + o;
        float a = 0.f;
#pragma unroll 8
        for (int j = 0; j < 32; ++j)
            a += hred[g * 32 + j] * w3p[(size_t)j * OD];
        atomicAdd(&out[(size_t)b * OD + o], a);
    }
}

extern "C" void kernel_launch(void* const* d_in, const int* in_sizes, int n_in,
                              void* d_out, int out_size, void* d_ws, size_t ws_size,
                              hipStream_t stream) {
    const float* x  = (const float*)d_in[0];
    const float* W1 = (const float*)d_in[1];
    const float* b1 = (const float*)d_in[2];
    const float* W2 = (const float*)d_in[3];
    const float* b2 = (const float*)d_in[4];
    const float* W3 = (const float*)d_in[5];
    const float* b3 = (const float*)d_in[6];
    float* out = (float*)d_out;

    _Float16* U   = (_Float16*)d_ws;                    // 2MB  (U' = xW1a + b1, f16)
    _Float16* V   = U + (size_t)BB * NN * HD;           // 2MB  (V  = xW1b, f16)
    _Float16* W2t = V + (size_t)BB * NN * HD;           // 512KB f16 [c][k]
    _Float16* W1t = W2t + (size_t)HD * HD;              // 256KB f16 [h][k]
    _Float16* x16 = W1t + (size_t)HD * (IND * 2);       // 512KB f16 [b][n][k]

    hipLaunchKernelGGL(kprepA, dim3(112), dim3(256), 0, stream,
                       W2, W2t, b3, out, W1, W1t, x, x16);
    hipLaunchKernelGGL(k1m, dim3(4, 64), dim3(512), 0, stream, x16, W1t, b1, U, V);
    hipLaunchKernelGGL(k2, dim3(8, 64), dim3(512), 0, stream, U, V, W2t, b2, W3, out);
}